// Round 1
// baseline (1122.936 us; speedup 1.0000x reference)
//
#include <hip/hip_runtime.h>
#include <hip/hip_bf16.h>

// ---------------------------------------------------------------------------
// GCN edge prediction: 3x (GEMM -> normalized scatter-add -> self-loop+bias[+relu])
// then dot-product decode over label edges. All fp32.
// ---------------------------------------------------------------------------

__global__ void count_deg_kernel(const int* __restrict__ dst, float* __restrict__ deg, int E) {
    int e = blockIdx.x * blockDim.x + threadIdx.x;
    if (e < E) atomicAdd(&deg[dst[e]], 1.0f);
}

__global__ void make_dinv_kernel(float* __restrict__ deg, int n) {
    int v = blockIdx.x * blockDim.x + threadIdx.x;
    if (v < n) {
        float d = deg[v] + 1.0f;           // +1 self-loop; always >= 1
        deg[v] = 1.0f / sqrtf(d);
    }
}

// Tiled fp32 GEMM: out[M][128] = A[M][K] @ W[K][128].  BM=64, BN=128, BK=32.
// 256 threads/block; each thread computes 8 rows x 4 cols.
#define GEMM_BK 32
__global__ __launch_bounds__(256) void gemm_f32_kernel(const float* __restrict__ A,
                                                       const float* __restrict__ W,
                                                       float* __restrict__ out,
                                                       int M, int K) {
    __shared__ float As[64][GEMM_BK];    // [m][k]  (reads are wave-broadcast)
    __shared__ float Bs[GEMM_BK][128];   // [k][n]

    const int t = threadIdx.x;
    const int block_row = blockIdx.x * 64;
    const int col  = (t & 31) * 4;       // 4 consecutive cols (float4)
    const int row0 = (t >> 5) * 8;       // 8 consecutive rows

    float acc[8][4];
#pragma unroll
    for (int i = 0; i < 8; ++i)
#pragma unroll
        for (int j = 0; j < 4; ++j) acc[i][j] = 0.0f;

    for (int k0 = 0; k0 < K; k0 += GEMM_BK) {
        // Load A tile 64x32 as float4 (2 per thread)
#pragma unroll
        for (int i = 0; i < 2; ++i) {
            int idx = t + i * 256;             // float4 index
            int m = idx >> 3;                  // 8 float4 per row
            int kq = (idx & 7) * 4;
            int gr = block_row + m;
            float4 v = make_float4(0.f, 0.f, 0.f, 0.f);
            if (gr < M) v = *reinterpret_cast<const float4*>(&A[(size_t)gr * K + k0 + kq]);
            *reinterpret_cast<float4*>(&As[m][kq]) = v;
        }
        // Load B tile 32x128 as float4 (4 per thread)
#pragma unroll
        for (int i = 0; i < 4; ++i) {
            int idx = t + i * 256;             // float4 index
            int kk = idx >> 5;                 // 32 float4 per row
            int nn = (idx & 31) * 4;
            *reinterpret_cast<float4*>(&Bs[kk][nn]) =
                *reinterpret_cast<const float4*>(&W[(size_t)(k0 + kk) * 128 + nn]);
        }
        __syncthreads();

#pragma unroll 8
        for (int kk = 0; kk < GEMM_BK; ++kk) {
            float4 bv = *reinterpret_cast<const float4*>(&Bs[kk][col]);
#pragma unroll
            for (int i = 0; i < 8; ++i) {
                float av = As[row0 + i][kk];
                acc[i][0] += av * bv.x;
                acc[i][1] += av * bv.y;
                acc[i][2] += av * bv.z;
                acc[i][3] += av * bv.w;
            }
        }
        __syncthreads();
    }

#pragma unroll
    for (int i = 0; i < 8; ++i) {
        int gr = block_row + row0 + i;
        if (gr < M) {
            float4 v = make_float4(acc[i][0], acc[i][1], acc[i][2], acc[i][3]);
            *reinterpret_cast<float4*>(&out[(size_t)gr * 128 + col]) = v;
        }
    }
}

// One 64-lane wave per edge; each lane handles 2 features.
__global__ __launch_bounds__(256) void scatter_edges_kernel(const int* __restrict__ src,
                                                            const int* __restrict__ dst,
                                                            const float* __restrict__ dinv,
                                                            const float* __restrict__ h,
                                                            float* __restrict__ agg, int E) {
    int gid = blockIdx.x * blockDim.x + threadIdx.x;
    int e = gid >> 6;
    int lane = gid & 63;
    if (e >= E) return;
    int u = src[e], v = dst[e];
    float w = dinv[u] * dinv[v];
    float2 hv = *reinterpret_cast<const float2*>(&h[(size_t)u * 128 + lane * 2]);
    float* ap = &agg[(size_t)v * 128 + lane * 2];
    atomicAdd(ap,     w * hv.x);
    atomicAdd(ap + 1, w * hv.y);
}

// out[v,f] = [relu]( agg[v,f] + dinv[v]^2 * h[v,f] + b[f] )   (in-place over agg ok)
__global__ __launch_bounds__(256) void finalize_kernel(const float* __restrict__ agg,
                                                       const float* __restrict__ h,
                                                       const float* __restrict__ dinv,
                                                       const float* __restrict__ bias,
                                                       float* __restrict__ out,
                                                       int n, int do_relu) {
    int idx = blockIdx.x * blockDim.x + threadIdx.x;
    if (idx >= n * 128) return;
    int v = idx >> 7, f = idx & 127;
    float dv = dinv[v];
    float val = agg[idx] + dv * dv * h[idx] + bias[f];
    if (do_relu) val = fmaxf(val, 0.0f);
    out[idx] = val;
}

// One wave per label edge: dot(z[a], z[b]) over 128 dims.
__global__ __launch_bounds__(256) void decode_kernel(const int* __restrict__ ia,
                                                     const int* __restrict__ ib,
                                                     const float* __restrict__ z,
                                                     float* __restrict__ out, int EL) {
    int gid = blockIdx.x * blockDim.x + threadIdx.x;
    int e = gid >> 6;
    int lane = gid & 63;
    if (e >= EL) return;
    int a = ia[e], b = ib[e];
    float2 za = *reinterpret_cast<const float2*>(&z[(size_t)a * 128 + lane * 2]);
    float2 zb = *reinterpret_cast<const float2*>(&z[(size_t)b * 128 + lane * 2]);
    float s = za.x * zb.x + za.y * zb.y;
#pragma unroll
    for (int off = 32; off > 0; off >>= 1) s += __shfl_down(s, off, 64);
    if (lane == 0) out[e] = s;
}

extern "C" void kernel_launch(void* const* d_in, const int* in_sizes, int n_in,
                              void* d_out, int out_size, void* d_ws, size_t ws_size,
                              hipStream_t stream) {
    const float* x   = (const float*)d_in[0];
    const int*   ei  = (const int*)d_in[1];
    const int*   eli = (const int*)d_in[2];
    const float* W0  = (const float*)d_in[3];
    const float* b0  = (const float*)d_in[4];
    const float* W1  = (const float*)d_in[5];
    const float* b1  = (const float*)d_in[6];
    const float* W2  = (const float*)d_in[7];
    const float* b2  = (const float*)d_in[8];
    float* out = (float*)d_out;

    const int H    = in_sizes[4];            // 128
    const int F_in = in_sizes[3] / H;        // 256
    const int n    = in_sizes[0] / F_in;     // 50000
    const int E    = in_sizes[1] / 2;        // 320000
    const int EL   = in_sizes[2] / 2;        // 200000

    const int* src = ei;
    const int* dst = ei + E;
    const int* la  = eli;
    const int* lb  = eli + EL;

    char* ws = (char*)d_ws;
    float* dinv = (float*)ws;
    size_t off0 = ((size_t)n * 4 + 255) & ~(size_t)255;
    size_t bsz  = ((size_t)n * 128 * 4 + 255) & ~(size_t)255;
    float* bufA = (float*)(ws + off0);          // GEMM output h
    float* bufB = (float*)(ws + off0 + bsz);    // agg / layer output

    const int T = 256;
    dim3 blk(T);

    // degree + normalization (shared by all layers)
    hipMemsetAsync(dinv, 0, (size_t)n * 4, stream);
    count_deg_kernel<<<(E + T - 1) / T, blk, 0, stream>>>(dst, dinv, E);
    make_dinv_kernel<<<(n + T - 1) / T, blk, 0, stream>>>(dinv, n);

    const int gemm_blocks = (n + 63) / 64;
    const int edge_blocks = (int)(((long long)E * 64 + T - 1) / T);
    const int node_blocks = (int)(((long long)n * 128 + T - 1) / T);

    // ---- layer 0: x(256) -> 128, relu
    gemm_f32_kernel<<<gemm_blocks, blk, 0, stream>>>(x, W0, bufA, n, F_in);
    hipMemsetAsync(bufB, 0, (size_t)n * 128 * 4, stream);
    scatter_edges_kernel<<<edge_blocks, blk, 0, stream>>>(src, dst, dinv, bufA, bufB, E);
    finalize_kernel<<<node_blocks, blk, 0, stream>>>(bufB, bufA, dinv, b0, bufB, n, 1);

    // ---- layer 1: 128 -> 128, relu
    gemm_f32_kernel<<<gemm_blocks, blk, 0, stream>>>(bufB, W1, bufA, n, H);
    hipMemsetAsync(bufB, 0, (size_t)n * 128 * 4, stream);
    scatter_edges_kernel<<<edge_blocks, blk, 0, stream>>>(src, dst, dinv, bufA, bufB, E);
    finalize_kernel<<<node_blocks, blk, 0, stream>>>(bufB, bufA, dinv, b1, bufB, n, 1);

    // ---- layer 2: 128 -> 128, no activation
    gemm_f32_kernel<<<gemm_blocks, blk, 0, stream>>>(bufB, W2, bufA, n, H);
    hipMemsetAsync(bufB, 0, (size_t)n * 128 * 4, stream);
    scatter_edges_kernel<<<edge_blocks, blk, 0, stream>>>(src, dst, dinv, bufA, bufB, E);
    finalize_kernel<<<node_blocks, blk, 0, stream>>>(bufB, bufA, dinv, b2, bufB, n, 0);

    // ---- decode
    const int dec_blocks = (int)(((long long)EL * 64 + T - 1) / T);
    decode_kernel<<<dec_blocks, blk, 0, stream>>>(la, lb, bufB, out, EL);
}

// Round 2
// 415.509 us; speedup vs baseline: 2.7026x; 2.7026x over previous
//
#include <hip/hip_runtime.h>
#include <hip/hip_bf16.h>

// ---------------------------------------------------------------------------
// GCN edge prediction, CSR-gather version.
//   per launch: indegree count -> exclusive scan -> CSR fill
//   per layer : GEMM -> wave-per-node gather (neighbors + self-loop + bias [+relu])
//   decode    : wave-per-label-edge dot product
// ---------------------------------------------------------------------------

__global__ void count_deg_kernel(const int* __restrict__ dst, int* __restrict__ deg, int E) {
    int e = blockIdx.x * blockDim.x + threadIdx.x;
    if (e < E) atomicAdd(&deg[dst[e]], 1);
}

// In-place exclusive scan, hierarchical. Block = 1024 elements.
__global__ __launch_bounds__(1024) void scan1_kernel(int* __restrict__ data,
                                                     int* __restrict__ sums, int n) {
    __shared__ int tmp[1024];
    int t = threadIdx.x;
    int idx = blockIdx.x * 1024 + t;
    int val = (idx < n) ? data[idx] : 0;
    tmp[t] = val;
    __syncthreads();
#pragma unroll
    for (int off = 1; off < 1024; off <<= 1) {
        int v = (t >= off) ? tmp[t - off] : 0;
        __syncthreads();
        tmp[t] += v;
        __syncthreads();
    }
    if (idx < n) data[idx] = tmp[t] - val;         // exclusive
    if (t == 1023) sums[blockIdx.x] = tmp[t];      // block total
}

// Exclusive scan of <=64 block sums in one wave.
__global__ void scan2_kernel(int* __restrict__ sums, int nb) {
    int lane = threadIdx.x & 63;
    int v = (lane < nb) ? sums[lane] : 0;
    int orig = v;
#pragma unroll
    for (int d = 1; d < 64; d <<= 1) {
        int t2 = __shfl_up(v, d, 64);
        if (lane >= d) v += t2;
    }
    if (lane < nb) sums[lane] = v - orig;
}

__global__ __launch_bounds__(1024) void scan3_kernel(int* __restrict__ data,
                                                     const int* __restrict__ sums, int n) {
    int idx = blockIdx.x * 1024 + threadIdx.x;
    if (idx < n && blockIdx.x > 0) data[idx] += sums[blockIdx.x];
}

// dinv[v] = 1/sqrt(indeg+1), indeg from offset diffs.
__global__ void make_dinv_kernel(const int* __restrict__ off, float* __restrict__ dinv,
                                 int n, int E) {
    int v = blockIdx.x * blockDim.x + threadIdx.x;
    if (v < n) {
        int o1 = (v + 1 < n) ? off[v + 1] : E;
        float d = (float)(o1 - off[v]) + 1.0f;
        dinv[v] = 1.0f / sqrtf(d);
    }
}

__global__ void csr_fill_kernel(const int* __restrict__ src, const int* __restrict__ dst,
                                const int* __restrict__ off, int* __restrict__ fill,
                                int* __restrict__ csr_src, int E) {
    int e = blockIdx.x * blockDim.x + threadIdx.x;
    if (e >= E) return;
    int d = dst[e];
    int pos = atomicAdd(&fill[d], 1);
    csr_src[off[d] + pos] = src[e];
}

// Tiled fp32 GEMM: out[M][128] = A[M][K] @ W[K][128].  BM=64, BN=128, BK=32.
#define GEMM_BK 32
__global__ __launch_bounds__(256) void gemm_f32_kernel(const float* __restrict__ A,
                                                       const float* __restrict__ W,
                                                       float* __restrict__ out,
                                                       int M, int K) {
    __shared__ float As[64][GEMM_BK];
    __shared__ float Bs[GEMM_BK][128];

    const int t = threadIdx.x;
    const int block_row = blockIdx.x * 64;
    const int col  = (t & 31) * 4;
    const int row0 = (t >> 5) * 8;

    float acc[8][4];
#pragma unroll
    for (int i = 0; i < 8; ++i)
#pragma unroll
        for (int j = 0; j < 4; ++j) acc[i][j] = 0.0f;

    for (int k0 = 0; k0 < K; k0 += GEMM_BK) {
#pragma unroll
        for (int i = 0; i < 2; ++i) {
            int idx = t + i * 256;
            int m = idx >> 3;
            int kq = (idx & 7) * 4;
            int gr = block_row + m;
            float4 v = make_float4(0.f, 0.f, 0.f, 0.f);
            if (gr < M) v = *reinterpret_cast<const float4*>(&A[(size_t)gr * K + k0 + kq]);
            *reinterpret_cast<float4*>(&As[m][kq]) = v;
        }
#pragma unroll
        for (int i = 0; i < 4; ++i) {
            int idx = t + i * 256;
            int kk = idx >> 5;
            int nn = (idx & 31) * 4;
            *reinterpret_cast<float4*>(&Bs[kk][nn]) =
                *reinterpret_cast<const float4*>(&W[(size_t)(k0 + kk) * 128 + nn]);
        }
        __syncthreads();

#pragma unroll 8
        for (int kk = 0; kk < GEMM_BK; ++kk) {
            float4 bv = *reinterpret_cast<const float4*>(&Bs[kk][col]);
#pragma unroll
            for (int i = 0; i < 8; ++i) {
                float av = As[row0 + i][kk];
                acc[i][0] += av * bv.x;
                acc[i][1] += av * bv.y;
                acc[i][2] += av * bv.z;
                acc[i][3] += av * bv.w;
            }
        }
        __syncthreads();
    }

#pragma unroll
    for (int i = 0; i < 8; ++i) {
        int gr = block_row + row0 + i;
        if (gr < M) {
            float4 v = make_float4(acc[i][0], acc[i][1], acc[i][2], acc[i][3]);
            *reinterpret_cast<float4*>(&out[(size_t)gr * 128 + col]) = v;
        }
    }
}

// One 64-lane wave per node; lane handles 2 features. Neighbors via CSR,
// self-loop + bias + optional relu fused.
__global__ __launch_bounds__(256) void gather_kernel(const int* __restrict__ off,
                                                     const int* __restrict__ csr_src,
                                                     const float* __restrict__ dinv,
                                                     const float* __restrict__ h,
                                                     const float* __restrict__ bias,
                                                     float* __restrict__ out,
                                                     int n, int E, int do_relu) {
    int gid = blockIdx.x * blockDim.x + threadIdx.x;
    int v = gid >> 6;
    int lane = gid & 63;
    if (v >= n) return;

    int o0 = off[v];
    int o1 = (v + 1 < n) ? off[v + 1] : E;
    float dv = dinv[v];

    float ax = 0.0f, ay = 0.0f;
    for (int j = o0; j < o1; ++j) {
        int s = csr_src[j];                       // wave-broadcast load
        float w = dinv[s] * dv;
        float2 hv = *reinterpret_cast<const float2*>(&h[(size_t)s * 128 + lane * 2]);
        ax += w * hv.x;
        ay += w * hv.y;
    }
    float2 hs = *reinterpret_cast<const float2*>(&h[(size_t)v * 128 + lane * 2]);
    float2 bb = *reinterpret_cast<const float2*>(&bias[lane * 2]);
    float ox = ax + dv * dv * hs.x + bb.x;
    float oy = ay + dv * dv * hs.y + bb.y;
    if (do_relu) { ox = fmaxf(ox, 0.0f); oy = fmaxf(oy, 0.0f); }
    *reinterpret_cast<float2*>(&out[(size_t)v * 128 + lane * 2]) = make_float2(ox, oy);
}

// One wave per label edge: dot(z[a], z[b]) over 128 dims.
__global__ __launch_bounds__(256) void decode_kernel(const int* __restrict__ ia,
                                                     const int* __restrict__ ib,
                                                     const float* __restrict__ z,
                                                     float* __restrict__ out, int EL) {
    int gid = blockIdx.x * blockDim.x + threadIdx.x;
    int e = gid >> 6;
    int lane = gid & 63;
    if (e >= EL) return;
    int a = ia[e], b = ib[e];
    float2 za = *reinterpret_cast<const float2*>(&z[(size_t)a * 128 + lane * 2]);
    float2 zb = *reinterpret_cast<const float2*>(&z[(size_t)b * 128 + lane * 2]);
    float s = za.x * zb.x + za.y * zb.y;
#pragma unroll
    for (int off = 32; off > 0; off >>= 1) s += __shfl_down(s, off, 64);
    if (lane == 0) out[e] = s;
}

extern "C" void kernel_launch(void* const* d_in, const int* in_sizes, int n_in,
                              void* d_out, int out_size, void* d_ws, size_t ws_size,
                              hipStream_t stream) {
    const float* x   = (const float*)d_in[0];
    const int*   ei  = (const int*)d_in[1];
    const int*   eli = (const int*)d_in[2];
    const float* W0  = (const float*)d_in[3];
    const float* b0  = (const float*)d_in[4];
    const float* W1  = (const float*)d_in[5];
    const float* b1  = (const float*)d_in[6];
    const float* W2  = (const float*)d_in[7];
    const float* b2  = (const float*)d_in[8];
    float* out = (float*)d_out;

    const int H    = in_sizes[4];            // 128
    const int F_in = in_sizes[3] / H;        // 256
    const int n    = in_sizes[0] / F_in;     // 50000
    const int E    = in_sizes[1] / 2;        // 320000
    const int EL   = in_sizes[2] / 2;        // 200000

    const int* src = ei;
    const int* dst = ei + E;
    const int* la  = eli;
    const int* lb  = eli + EL;

    // workspace layout
    char* ws = (char*)d_ws;
    size_t p = 0;
    auto alloc = [&](size_t bytes) { char* r = ws + p; p = (p + bytes + 255) & ~(size_t)255; return r; };
    float* dinv    = (float*)alloc((size_t)n * 4);
    int*   off     = (int*)  alloc((size_t)n * 4);
    int*   csr_src = (int*)  alloc((size_t)E * 4);
    int*   sums    = (int*)  alloc(64 * 4);
    float* bufA    = (float*)alloc((size_t)n * 128 * 4);
    float* bufB    = (float*)alloc((size_t)n * 128 * 4);
    int*   fill    = (int*)bufB;   // alias: only used during CSR build, before bufB written

    const int T = 256;
    dim3 blk(T);

    // ---- CSR build + normalization
    hipMemsetAsync(off, 0, (size_t)n * 4, stream);
    hipMemsetAsync(fill, 0, (size_t)n * 4, stream);
    count_deg_kernel<<<(E + T - 1) / T, blk, 0, stream>>>(dst, off, E);
    int nb = (n + 1023) / 1024;
    scan1_kernel<<<nb, 1024, 0, stream>>>(off, sums, n);
    scan2_kernel<<<1, 64, 0, stream>>>(sums, nb);
    scan3_kernel<<<nb, 1024, 0, stream>>>(off, sums, n);
    make_dinv_kernel<<<(n + T - 1) / T, blk, 0, stream>>>(off, dinv, n, E);
    csr_fill_kernel<<<(E + T - 1) / T, blk, 0, stream>>>(src, dst, off, fill, csr_src, E);

    const int gemm_blocks   = (n + 63) / 64;
    const int gather_blocks = (int)(((long long)n * 64 + T - 1) / T);

    // ---- layer 0: x(256) -> 128, relu
    gemm_f32_kernel<<<gemm_blocks, blk, 0, stream>>>(x, W0, bufA, n, F_in);
    gather_kernel<<<gather_blocks, blk, 0, stream>>>(off, csr_src, dinv, bufA, b0, bufB, n, E, 1);

    // ---- layer 1: 128 -> 128, relu
    gemm_f32_kernel<<<gemm_blocks, blk, 0, stream>>>(bufB, W1, bufA, n, H);
    gather_kernel<<<gather_blocks, blk, 0, stream>>>(off, csr_src, dinv, bufA, b1, bufB, n, E, 1);

    // ---- layer 2: 128 -> 128, no activation
    gemm_f32_kernel<<<gemm_blocks, blk, 0, stream>>>(bufB, W2, bufA, n, H);
    gather_kernel<<<gather_blocks, blk, 0, stream>>>(off, csr_src, dinv, bufA, b2, bufB, n, E, 0);

    // ---- decode
    const int dec_blocks = (int)(((long long)EL * 64 + T - 1) / T);
    decode_kernel<<<dec_blocks, blk, 0, stream>>>(la, lb, bufB, out, EL);
}

// Round 4
// 384.123 us; speedup vs baseline: 2.9234x; 1.0817x over previous
//
#include <hip/hip_runtime.h>
#include <hip/hip_bf16.h>

// ---------------------------------------------------------------------------
// GCN edge prediction.
//   CSR build (count -> scan -> fill) once per launch.
//   Per layer: split-bf16 MFMA GEMM (3-term: ah*bh + ah*bl + al*bh, fp32 acc)
//              -> wave-per-node CSR gather (+self loop, +bias, [relu]).
//   Decode: wave-per-label-edge dot product.
// ---------------------------------------------------------------------------

typedef __attribute__((ext_vector_type(8))) short short8v;   // 8 bf16 = 4 VGPR
typedef __attribute__((ext_vector_type(4))) short short4v;   // 4 bf16
typedef __attribute__((ext_vector_type(4))) float f32x4;

__device__ inline unsigned bf16_rne(float f) {
    unsigned u = __float_as_uint(f);
    return (u + 0x7FFF + ((u >> 16) & 1)) >> 16;   // round-to-nearest-even
}

// ---------------- CSR build ----------------

__global__ void count_deg_kernel(const int* __restrict__ dst, int* __restrict__ deg, int E) {
    int e = blockIdx.x * blockDim.x + threadIdx.x;
    if (e < E) atomicAdd(&deg[dst[e]], 1);
}

__global__ __launch_bounds__(1024) void scan1_kernel(int* __restrict__ data,
                                                     int* __restrict__ sums, int n) {
    __shared__ int tmp[1024];
    int t = threadIdx.x;
    int idx = blockIdx.x * 1024 + t;
    int val = (idx < n) ? data[idx] : 0;
    tmp[t] = val;
    __syncthreads();
#pragma unroll
    for (int off = 1; off < 1024; off <<= 1) {
        int v = (t >= off) ? tmp[t - off] : 0;
        __syncthreads();
        tmp[t] += v;
        __syncthreads();
    }
    if (idx < n) data[idx] = tmp[t] - val;
    if (t == 1023) sums[blockIdx.x] = tmp[t];
}

__global__ void scan2_kernel(int* __restrict__ sums, int nb) {
    int lane = threadIdx.x & 63;
    int v = (lane < nb) ? sums[lane] : 0;
    int orig = v;
#pragma unroll
    for (int d = 1; d < 64; d <<= 1) {
        int t2 = __shfl_up(v, d, 64);
        if (lane >= d) v += t2;
    }
    if (lane < nb) sums[lane] = v - orig;
}

__global__ __launch_bounds__(1024) void scan3_kernel(int* __restrict__ data,
                                                     const int* __restrict__ sums, int n) {
    int idx = blockIdx.x * 1024 + threadIdx.x;
    if (idx < n && blockIdx.x > 0) data[idx] += sums[blockIdx.x];
}

__global__ void make_dinv_kernel(const int* __restrict__ off, float* __restrict__ dinv,
                                 int n, int E) {
    int v = blockIdx.x * blockDim.x + threadIdx.x;
    if (v < n) {
        int o1 = (v + 1 < n) ? off[v + 1] : E;
        float d = (float)(o1 - off[v]) + 1.0f;
        dinv[v] = 1.0f / sqrtf(d);
    }
}

__global__ void csr_fill_kernel(const int* __restrict__ src, const int* __restrict__ dst,
                                const int* __restrict__ off, int* __restrict__ fill,
                                int* __restrict__ csr_src, int E) {
    int e = blockIdx.x * blockDim.x + threadIdx.x;
    if (e >= E) return;
    int d = dst[e];
    int pos = atomicAdd(&fill[d], 1);
    csr_src[off[d] + pos] = src[e];
}

// ---------------- W split + transpose (once per launch, tiny) ----------------
// W[K][128] fp32 -> Wh/Wl[128][K] bf16 (as short)

__global__ void split_w_kernel(const float* __restrict__ W, short* __restrict__ Wh,
                               short* __restrict__ Wl, int K) {
    int idx = blockIdx.x * blockDim.x + threadIdx.x;
    if (idx >= K * 128) return;
    int k = idx >> 7, col = idx & 127;
    float f = W[idx];
    unsigned h = bf16_rne(f);
    float fh = __uint_as_float(h << 16);
    unsigned l = bf16_rne(f - fh);
    Wh[col * K + k] = (short)h;
    Wl[col * K + k] = (short)l;
}

// ---------------- split-bf16 MFMA GEMM ----------------
// out[M][128] = A[M][K] @ W[K][128];  Wt given as [128][K] bf16 hi/lo.
// BM=128, BN=128, BK=64; 256 threads = 4 waves; wave w: rows w*32..w*32+31.
// LDS 16B-unit XOR swizzle: kbyte ^= (row&7)<<4 (write and read sides).

#define SWZ(row, kbyte) (((row) * 128) + ((kbyte) ^ (((row) & 7) << 4)))

__global__ __launch_bounds__(256) void gemm_mfma_kernel(const float* __restrict__ A,
                                                        const short* __restrict__ Wh_g,
                                                        const short* __restrict__ Wl_g,
                                                        float* __restrict__ out,
                                                        int M, int K) {
    __shared__ __align__(16) char smem[65536];
    char* Ah = smem;            // [128 rows][128 B]  (64 bf16 per row)
    char* Al = smem + 16384;
    char* Bh = smem + 32768;    // [128 cols][128 B]
    char* Bl = smem + 49152;

    const int t = threadIdx.x;
    const int lane = t & 63;
    const int w = t >> 6;
    const int block_row = blockIdx.x * 128;

    f32x4 acc[2][8];
#pragma unroll
    for (int m = 0; m < 2; ++m)
#pragma unroll
        for (int c = 0; c < 8; ++c) acc[m][c] = (f32x4){0.f, 0.f, 0.f, 0.f};

    for (int k0 = 0; k0 < K; k0 += 64) {
        __syncthreads();   // previous iteration's frag reads done before overwrite

        // ---- stage A tile 128x64 fp32 -> bf16 hi/lo (8 float4 per thread)
#pragma unroll
        for (int i = 0; i < 8; ++i) {
            int idx = t + i * 256;          // 0..2047 float4 slots
            int row = idx >> 4;             // 16 float4 per row
            int kq  = (idx & 15) << 2;      // element 0..60
            int grow = block_row + row;
            float4 v = make_float4(0.f, 0.f, 0.f, 0.f);
            if (grow < M) v = *reinterpret_cast<const float4*>(&A[(size_t)grow * K + k0 + kq]);
            short4v hv, lv;
            float f[4] = {v.x, v.y, v.z, v.w};
#pragma unroll
            for (int j = 0; j < 4; ++j) {
                unsigned h = bf16_rne(f[j]);
                float fh = __uint_as_float(h << 16);
                unsigned l = bf16_rne(f[j] - fh);
                hv[j] = (short)h;
                lv[j] = (short)l;
            }
            int off = SWZ(row, kq * 2);     // 8B-aligned; XOR flips bits 4..6 only
            *reinterpret_cast<short4v*>(&Ah[off]) = hv;
            *reinterpret_cast<short4v*>(&Al[off]) = lv;
        }
        // ---- stage B slice [128 cols][64 k] bf16 hi/lo (4 x 16B per thread each)
#pragma unroll
        for (int i = 0; i < 4; ++i) {
            int idx = t + i * 256;          // 0..1023 16B units
            int row = idx >> 3;             // col
            int u   = idx & 7;              // 16B unit within row
            size_t g = (size_t)row * K + k0 + u * 8;
            short8v hv = *reinterpret_cast<const short8v*>(&Wh_g[g]);
            short8v lv = *reinterpret_cast<const short8v*>(&Wl_g[g]);
            int off = SWZ(row, u * 16);
            *reinterpret_cast<short8v*>(&Bh[off]) = hv;
            *reinterpret_cast<short8v*>(&Bl[off]) = lv;
        }
        __syncthreads();

        // ---- a-fragments for this wave's 32 rows
        short8v ah[2][2], al[2][2];
#pragma unroll
        for (int m = 0; m < 2; ++m)
#pragma unroll
            for (int ks = 0; ks < 2; ++ks) {
                int row = w * 32 + m * 16 + (lane & 15);
                int kb  = ks * 64 + (lane >> 4) * 16;
                ah[m][ks] = *reinterpret_cast<const short8v*>(&Ah[SWZ(row, kb)]);
                al[m][ks] = *reinterpret_cast<const short8v*>(&Al[SWZ(row, kb)]);
            }

#pragma unroll
        for (int c = 0; c < 8; ++c) {
            short8v bh[2], bl[2];
#pragma unroll
            for (int ks = 0; ks < 2; ++ks) {
                int rb = c * 16 + (lane & 15);
                int kb = ks * 64 + (lane >> 4) * 16;
                bh[ks] = *reinterpret_cast<const short8v*>(&Bh[SWZ(rb, kb)]);
                bl[ks] = *reinterpret_cast<const short8v*>(&Bl[SWZ(rb, kb)]);
            }
#pragma unroll
            for (int m = 0; m < 2; ++m)
#pragma unroll
                for (int ks = 0; ks < 2; ++ks) {
                    acc[m][c] = __builtin_amdgcn_mfma_f32_16x16x32_bf16(ah[m][ks], bh[ks], acc[m][c], 0, 0, 0);
                    acc[m][c] = __builtin_amdgcn_mfma_f32_16x16x32_bf16(ah[m][ks], bl[ks], acc[m][c], 0, 0, 0);
                    acc[m][c] = __builtin_amdgcn_mfma_f32_16x16x32_bf16(al[m][ks], bh[ks], acc[m][c], 0, 0, 0);
                }
        }
    }

    // ---- epilogue: C/D layout col=lane&15, row=(lane>>4)*4+reg
#pragma unroll
    for (int m = 0; m < 2; ++m)
#pragma unroll
        for (int c = 0; c < 8; ++c)
#pragma unroll
            for (int r = 0; r < 4; ++r) {
                int row = block_row + w * 32 + m * 16 + (lane >> 4) * 4 + r;
                int col = c * 16 + (lane & 15);
                if (row < M) out[(size_t)row * 128 + col] = acc[m][c][r];
            }
}

// ---------------- gather / decode ----------------

__global__ __launch_bounds__(256) void gather_kernel(const int* __restrict__ off,
                                                     const int* __restrict__ csr_src,
                                                     const float* __restrict__ dinv,
                                                     const float* __restrict__ h,
                                                     const float* __restrict__ bias,
                                                     float* __restrict__ out,
                                                     int n, int E, int do_relu) {
    int gid = blockIdx.x * blockDim.x + threadIdx.x;
    int v = gid >> 6;
    int lane = gid & 63;
    if (v >= n) return;

    int o0 = off[v];
    int o1 = (v + 1 < n) ? off[v + 1] : E;
    float dv = dinv[v];

    float ax = 0.0f, ay = 0.0f;
    for (int j = o0; j < o1; ++j) {
        int s = csr_src[j];
        float wgt = dinv[s] * dv;
        float2 hv = *reinterpret_cast<const float2*>(&h[(size_t)s * 128 + lane * 2]);
        ax += wgt * hv.x;
        ay += wgt * hv.y;
    }
    float2 hs = *reinterpret_cast<const float2*>(&h[(size_t)v * 128 + lane * 2]);
    float2 bb = *reinterpret_cast<const float2*>(&bias[lane * 2]);
    float ox = ax + dv * dv * hs.x + bb.x;
    float oy = ay + dv * dv * hs.y + bb.y;
    if (do_relu) { ox = fmaxf(ox, 0.0f); oy = fmaxf(oy, 0.0f); }
    *reinterpret_cast<float2*>(&out[(size_t)v * 128 + lane * 2]) = make_float2(ox, oy);
}

__global__ __launch_bounds__(256) void decode_kernel(const int* __restrict__ ia,
                                                     const int* __restrict__ ib,
                                                     const float* __restrict__ z,
                                                     float* __restrict__ out, int EL) {
    int gid = blockIdx.x * blockDim.x + threadIdx.x;
    int e = gid >> 6;
    int lane = gid & 63;
    if (e >= EL) return;
    int a = ia[e], b = ib[e];
    float2 za = *reinterpret_cast<const float2*>(&z[(size_t)a * 128 + lane * 2]);
    float2 zb = *reinterpret_cast<const float2*>(&z[(size_t)b * 128 + lane * 2]);
    float s = za.x * zb.x + za.y * zb.y;
#pragma unroll
    for (int off = 32; off > 0; off >>= 1) s += __shfl_down(s, off, 64);
    if (lane == 0) out[e] = s;
}

// ---------------- host launch ----------------

extern "C" void kernel_launch(void* const* d_in, const int* in_sizes, int n_in,
                              void* d_out, int out_size, void* d_ws, size_t ws_size,
                              hipStream_t stream) {
    const float* x   = (const float*)d_in[0];
    const int*   ei  = (const int*)d_in[1];
    const int*   eli = (const int*)d_in[2];
    const float* W0  = (const float*)d_in[3];
    const float* b0  = (const float*)d_in[4];
    const float* W1  = (const float*)d_in[5];
    const float* b1  = (const float*)d_in[6];
    const float* W2  = (const float*)d_in[7];
    const float* b2  = (const float*)d_in[8];
    float* out = (float*)d_out;

    const int H    = in_sizes[4];            // 128
    const int F_in = in_sizes[3] / H;        // 256
    const int n    = in_sizes[0] / F_in;     // 50000
    const int E    = in_sizes[1] / 2;        // 320000
    const int EL   = in_sizes[2] / 2;        // 200000

    const int* src = ei;
    const int* dst = ei + E;
    const int* la  = eli;
    const int* lb  = eli + EL;

    char* ws = (char*)d_ws;
    size_t p = 0;
    auto alloc = [&](size_t bytes) { char* r = ws + p; p = (p + bytes + 255) & ~(size_t)255; return r; };
    float* dinv    = (float*)alloc((size_t)n * 4);
    int*   off     = (int*)  alloc((size_t)n * 4);
    int*   csr_src = (int*)  alloc((size_t)E * 4);
    int*   sums    = (int*)  alloc(64 * 4);
    short* W0h     = (short*)alloc((size_t)F_in * H * 2);
    short* W0l     = (short*)alloc((size_t)F_in * H * 2);
    short* W1h     = (short*)alloc((size_t)H * H * 2);
    short* W1l     = (short*)alloc((size_t)H * H * 2);
    short* W2h     = (short*)alloc((size_t)H * H * 2);
    short* W2l     = (short*)alloc((size_t)H * H * 2);
    float* bufA    = (float*)alloc((size_t)n * 128 * 4);
    float* bufB    = (float*)alloc((size_t)n * 128 * 4);
    int*   fill    = (int*)bufB;   // alias: only used during CSR build

    const int T = 256;
    dim3 blk(T);

    // ---- CSR build + normalization + weight split (independent work up front)
    hipMemsetAsync(off, 0, (size_t)n * 4, stream);
    hipMemsetAsync(fill, 0, (size_t)n * 4, stream);
    split_w_kernel<<<(F_in * H + T - 1) / T, blk, 0, stream>>>(W0, W0h, W0l, F_in);
    split_w_kernel<<<(H * H + T - 1) / T, blk, 0, stream>>>(W1, W1h, W1l, H);
    split_w_kernel<<<(H * H + T - 1) / T, blk, 0, stream>>>(W2, W2h, W2l, H);
    count_deg_kernel<<<(E + T - 1) / T, blk, 0, stream>>>(dst, off, E);
    int nb = (n + 1023) / 1024;
    scan1_kernel<<<nb, 1024, 0, stream>>>(off, sums, n);
    scan2_kernel<<<1, 64, 0, stream>>>(sums, nb);
    scan3_kernel<<<nb, 1024, 0, stream>>>(off, sums, n);
    make_dinv_kernel<<<(n + T - 1) / T, blk, 0, stream>>>(off, dinv, n, E);
    csr_fill_kernel<<<(E + T - 1) / T, blk, 0, stream>>>(src, dst, off, fill, csr_src, E);

    const int mblocks       = (n + 127) / 128;
    const int gather_blocks = (int)(((long long)n * 64 + T - 1) / T);

    // ---- layer 0: x(256) -> 128, relu
    gemm_mfma_kernel<<<mblocks, blk, 0, stream>>>(x, W0h, W0l, bufA, n, F_in);
    gather_kernel<<<gather_blocks, blk, 0, stream>>>(off, csr_src, dinv, bufA, b0, bufB, n, E, 1);

    // ---- layer 1: 128 -> 128, relu
    gemm_mfma_kernel<<<mblocks, blk, 0, stream>>>(bufB, W1h, W1l, bufA, n, H);
    gather_kernel<<<gather_blocks, blk, 0, stream>>>(off, csr_src, dinv, bufA, b1, bufB, n, E, 1);

    // ---- layer 2: 128 -> 128, no activation
    gemm_mfma_kernel<<<mblocks, blk, 0, stream>>>(bufB, W2h, W2l, bufA, n, H);
    gather_kernel<<<gather_blocks, blk, 0, stream>>>(off, csr_src, dinv, bufA, b2, bufB, n, E, 0);

    // ---- decode
    const int dec_blocks = (int)(((long long)EL * 64 + T - 1) / T);
    decode_kernel<<<dec_blocks, blk, 0, stream>>>(la, lb, bufB, out, EL);
}

// Round 5
// 342.651 us; speedup vs baseline: 3.2772x; 1.1210x over previous
//
#include <hip/hip_runtime.h>
#include <hip/hip_bf16.h>

// ---------------------------------------------------------------------------
// GCN edge prediction.
//   CSR build (count -> scan -> fill) once per launch.
//   Per layer: split-bf16 MFMA GEMM (3-term), epilogue scales rows by dinv ->
//              wave-per-node CSR gather of pre-scaled h' (sum + self, *dv,
//              +bias, [relu]); neighbor indices prefetched lane-parallel.
//   Decode: wave-per-label-edge dot product.
// ---------------------------------------------------------------------------

typedef __attribute__((ext_vector_type(8))) short short8v;   // 8 bf16 = 4 VGPR
typedef __attribute__((ext_vector_type(4))) short short4v;   // 4 bf16
typedef __attribute__((ext_vector_type(4))) float f32x4;

__device__ inline unsigned bf16_rne(float f) {
    unsigned u = __float_as_uint(f);
    return (u + 0x7FFF + ((u >> 16) & 1)) >> 16;   // round-to-nearest-even
}

// ---------------- CSR build ----------------

__global__ void count_deg_kernel(const int* __restrict__ dst, int* __restrict__ deg, int E) {
    int e = blockIdx.x * blockDim.x + threadIdx.x;
    if (e < E) atomicAdd(&deg[dst[e]], 1);
}

__global__ __launch_bounds__(1024) void scan1_kernel(int* __restrict__ data,
                                                     int* __restrict__ sums, int n) {
    __shared__ int tmp[1024];
    int t = threadIdx.x;
    int idx = blockIdx.x * 1024 + t;
    int val = (idx < n) ? data[idx] : 0;
    tmp[t] = val;
    __syncthreads();
#pragma unroll
    for (int off = 1; off < 1024; off <<= 1) {
        int v = (t >= off) ? tmp[t - off] : 0;
        __syncthreads();
        tmp[t] += v;
        __syncthreads();
    }
    if (idx < n) data[idx] = tmp[t] - val;
    if (t == 1023) sums[blockIdx.x] = tmp[t];
}

__global__ void scan2_kernel(int* __restrict__ sums, int nb) {
    int lane = threadIdx.x & 63;
    int v = (lane < nb) ? sums[lane] : 0;
    int orig = v;
#pragma unroll
    for (int d = 1; d < 64; d <<= 1) {
        int t2 = __shfl_up(v, d, 64);
        if (lane >= d) v += t2;
    }
    if (lane < nb) sums[lane] = v - orig;
}

__global__ __launch_bounds__(1024) void scan3_kernel(int* __restrict__ data,
                                                     const int* __restrict__ sums, int n) {
    int idx = blockIdx.x * 1024 + threadIdx.x;
    if (idx < n && blockIdx.x > 0) data[idx] += sums[blockIdx.x];
}

__global__ void make_dinv_kernel(const int* __restrict__ off, float* __restrict__ dinv,
                                 int n, int E) {
    int v = blockIdx.x * blockDim.x + threadIdx.x;
    if (v < n) {
        int o1 = (v + 1 < n) ? off[v + 1] : E;
        float d = (float)(o1 - off[v]) + 1.0f;
        dinv[v] = 1.0f / sqrtf(d);
    }
}

__global__ void csr_fill_kernel(const int* __restrict__ src, const int* __restrict__ dst,
                                const int* __restrict__ off, int* __restrict__ fill,
                                int* __restrict__ csr_src, int E) {
    int e = blockIdx.x * blockDim.x + threadIdx.x;
    if (e >= E) return;
    int d = dst[e];
    int pos = atomicAdd(&fill[d], 1);
    csr_src[off[d] + pos] = src[e];
}

// ---------------- W split + transpose (once per launch, tiny) ----------------

__global__ void split_w_kernel(const float* __restrict__ W, short* __restrict__ Wh,
                               short* __restrict__ Wl, int K) {
    int idx = blockIdx.x * blockDim.x + threadIdx.x;
    if (idx >= K * 128) return;
    int k = idx >> 7, col = idx & 127;
    float f = W[idx];
    unsigned h = bf16_rne(f);
    float fh = __uint_as_float(h << 16);
    unsigned l = bf16_rne(f - fh);
    Wh[col * K + k] = (short)h;
    Wl[col * K + k] = (short)l;
}

// ---------------- split-bf16 MFMA GEMM ----------------
// out[M][128] = dinv[row] * (A[M][K] @ W[K][128])

#define SWZ(row, kbyte) (((row) * 128) + ((kbyte) ^ (((row) & 7) << 4)))

__global__ __launch_bounds__(256) void gemm_mfma_kernel(const float* __restrict__ A,
                                                        const short* __restrict__ Wh_g,
                                                        const short* __restrict__ Wl_g,
                                                        const float* __restrict__ dinv,
                                                        float* __restrict__ out,
                                                        int M, int K) {
    __shared__ __align__(16) char smem[65536];
    char* Ah = smem;            // [128 rows][128 B]  (64 bf16 per row)
    char* Al = smem + 16384;
    char* Bh = smem + 32768;    // [128 cols][128 B]
    char* Bl = smem + 49152;

    const int t = threadIdx.x;
    const int lane = t & 63;
    const int w = t >> 6;
    const int block_row = blockIdx.x * 128;

    f32x4 acc[2][8];
#pragma unroll
    for (int m = 0; m < 2; ++m)
#pragma unroll
        for (int c = 0; c < 8; ++c) acc[m][c] = (f32x4){0.f, 0.f, 0.f, 0.f};

    for (int k0 = 0; k0 < K; k0 += 64) {
        __syncthreads();

        // ---- stage A tile 128x64 fp32 -> bf16 hi/lo
#pragma unroll
        for (int i = 0; i < 8; ++i) {
            int idx = t + i * 256;
            int row = idx >> 4;
            int kq  = (idx & 15) << 2;
            int grow = block_row + row;
            float4 v = make_float4(0.f, 0.f, 0.f, 0.f);
            if (grow < M) v = *reinterpret_cast<const float4*>(&A[(size_t)grow * K + k0 + kq]);
            short4v hv, lv;
            float f[4] = {v.x, v.y, v.z, v.w};
#pragma unroll
            for (int j = 0; j < 4; ++j) {
                unsigned h = bf16_rne(f[j]);
                float fh = __uint_as_float(h << 16);
                unsigned l = bf16_rne(f[j] - fh);
                hv[j] = (short)h;
                lv[j] = (short)l;
            }
            int off = SWZ(row, kq * 2);
            *reinterpret_cast<short4v*>(&Ah[off]) = hv;
            *reinterpret_cast<short4v*>(&Al[off]) = lv;
        }
        // ---- stage B slice [128 cols][64 k] bf16 hi/lo
#pragma unroll
        for (int i = 0; i < 4; ++i) {
            int idx = t + i * 256;
            int row = idx >> 3;
            int u   = idx & 7;
            size_t g = (size_t)row * K + k0 + u * 8;
            short8v hv = *reinterpret_cast<const short8v*>(&Wh_g[g]);
            short8v lv = *reinterpret_cast<const short8v*>(&Wl_g[g]);
            int off = SWZ(row, u * 16);
            *reinterpret_cast<short8v*>(&Bh[off]) = hv;
            *reinterpret_cast<short8v*>(&Bl[off]) = lv;
        }
        __syncthreads();

        short8v ah[2][2], al[2][2];
#pragma unroll
        for (int m = 0; m < 2; ++m)
#pragma unroll
            for (int ks = 0; ks < 2; ++ks) {
                int row = w * 32 + m * 16 + (lane & 15);
                int kb  = ks * 64 + (lane >> 4) * 16;
                ah[m][ks] = *reinterpret_cast<const short8v*>(&Ah[SWZ(row, kb)]);
                al[m][ks] = *reinterpret_cast<const short8v*>(&Al[SWZ(row, kb)]);
            }

#pragma unroll
        for (int c = 0; c < 8; ++c) {
            short8v bh[2], bl[2];
#pragma unroll
            for (int ks = 0; ks < 2; ++ks) {
                int rb = c * 16 + (lane & 15);
                int kb = ks * 64 + (lane >> 4) * 16;
                bh[ks] = *reinterpret_cast<const short8v*>(&Bh[SWZ(rb, kb)]);
                bl[ks] = *reinterpret_cast<const short8v*>(&Bl[SWZ(rb, kb)]);
            }
#pragma unroll
            for (int m = 0; m < 2; ++m)
#pragma unroll
                for (int ks = 0; ks < 2; ++ks) {
                    acc[m][c] = __builtin_amdgcn_mfma_f32_16x16x32_bf16(ah[m][ks], bh[ks], acc[m][c], 0, 0, 0);
                    acc[m][c] = __builtin_amdgcn_mfma_f32_16x16x32_bf16(ah[m][ks], bl[ks], acc[m][c], 0, 0, 0);
                    acc[m][c] = __builtin_amdgcn_mfma_f32_16x16x32_bf16(al[m][ks], bh[ks], acc[m][c], 0, 0, 0);
                }
        }
    }

    // ---- epilogue: scale row by dinv[row]; C/D layout col=lane&15, row=(lane>>4)*4+reg
#pragma unroll
    for (int m = 0; m < 2; ++m)
#pragma unroll
        for (int r = 0; r < 4; ++r) {
            int row = block_row + w * 32 + m * 16 + (lane >> 4) * 4 + r;
            float ds = (row < M) ? dinv[row] : 0.0f;
#pragma unroll
            for (int c = 0; c < 8; ++c) {
                int col = c * 16 + (lane & 15);
                if (row < M) out[(size_t)row * 128 + col] = acc[m][c][r] * ds;
            }
        }
}

// ---------------- gather ----------------
// out[v] = relu( dv * (sum_{s in N(v)} h'[s] + h'[v]) + bias ),  h' = dinv*h.
// Neighbor indices prefetched 64-at-a-time lane-parallel, distributed by shfl.

__global__ __launch_bounds__(256) void gather_kernel(const int* __restrict__ off,
                                                     const int* __restrict__ csr_src,
                                                     const float* __restrict__ dinv,
                                                     const float* __restrict__ hp,
                                                     const float* __restrict__ bias,
                                                     float* __restrict__ out,
                                                     int n, int E, int do_relu) {
    int gid = blockIdx.x * blockDim.x + threadIdx.x;
    int v = gid >> 6;
    int lane = gid & 63;
    if (v >= n) return;

    int o0 = off[v];
    int o1 = (v + 1 < n) ? off[v + 1] : E;

    const float2* __restrict__ hp2 = reinterpret_cast<const float2*>(hp);
    float2 sv = hp2[(size_t)v * 64 + lane];          // self row
    float ax = sv.x, ay = sv.y;
    float bx = 0.0f, by = 0.0f;

    for (int base = o0; base < o1; base += 64) {
        int cnt = min(64, o1 - base);
        int myidx = (lane < cnt) ? csr_src[base + lane] : 0;
        int j = 0;
        for (; j + 4 <= cnt; j += 4) {
            int i0 = __shfl(myidx, j,     64);
            int i1 = __shfl(myidx, j + 1, 64);
            int i2 = __shfl(myidx, j + 2, 64);
            int i3 = __shfl(myidx, j + 3, 64);
            float2 h0 = hp2[(size_t)i0 * 64 + lane];
            float2 h1 = hp2[(size_t)i1 * 64 + lane];
            float2 h2 = hp2[(size_t)i2 * 64 + lane];
            float2 h3 = hp2[(size_t)i3 * 64 + lane];
            ax += h0.x; ay += h0.y;
            bx += h1.x; by += h1.y;
            ax += h2.x; ay += h2.y;
            bx += h3.x; by += h3.y;
        }
        for (; j < cnt; ++j) {
            int s = __shfl(myidx, j, 64);
            float2 hv = hp2[(size_t)s * 64 + lane];
            ax += hv.x; ay += hv.y;
        }
    }

    float dv = dinv[v];
    float2 bb = *reinterpret_cast<const float2*>(&bias[lane * 2]);
    float ox = dv * (ax + bx) + bb.x;
    float oy = dv * (ay + by) + bb.y;
    if (do_relu) { ox = fmaxf(ox, 0.0f); oy = fmaxf(oy, 0.0f); }
    *reinterpret_cast<float2*>(&out[(size_t)v * 128 + lane * 2]) = make_float2(ox, oy);
}

// ---------------- decode ----------------

__global__ __launch_bounds__(256) void decode_kernel(const int* __restrict__ ia,
                                                     const int* __restrict__ ib,
                                                     const float* __restrict__ z,
                                                     float* __restrict__ out, int EL) {
    int gid = blockIdx.x * blockDim.x + threadIdx.x;
    int e = gid >> 6;
    int lane = gid & 63;
    if (e >= EL) return;
    int a = ia[e], b = ib[e];
    float2 za = *reinterpret_cast<const float2*>(&z[(size_t)a * 128 + lane * 2]);
    float2 zb = *reinterpret_cast<const float2*>(&z[(size_t)b * 128 + lane * 2]);
    float s = za.x * zb.x + za.y * zb.y;
#pragma unroll
    for (int off = 32; off > 0; off >>= 1) s += __shfl_down(s, off, 64);
    if (lane == 0) out[e] = s;
}

// ---------------- host launch ----------------

extern "C" void kernel_launch(void* const* d_in, const int* in_sizes, int n_in,
                              void* d_out, int out_size, void* d_ws, size_t ws_size,
                              hipStream_t stream) {
    const float* x   = (const float*)d_in[0];
    const int*   ei  = (const int*)d_in[1];
    const int*   eli = (const int*)d_in[2];
    const float* W0  = (const float*)d_in[3];
    const float* b0  = (const float*)d_in[4];
    const float* W1  = (const float*)d_in[5];
    const float* b1  = (const float*)d_in[6];
    const float* W2  = (const float*)d_in[7];
    const float* b2  = (const float*)d_in[8];
    float* out = (float*)d_out;

    const int H    = in_sizes[4];            // 128
    const int F_in = in_sizes[3] / H;        // 256
    const int n    = in_sizes[0] / F_in;     // 50000
    const int E    = in_sizes[1] / 2;        // 320000
    const int EL   = in_sizes[2] / 2;        // 200000

    const int* src = ei;
    const int* dst = ei + E;
    const int* la  = eli;
    const int* lb  = eli + EL;

    char* ws = (char*)d_ws;
    size_t p = 0;
    auto alloc = [&](size_t bytes) { char* r = ws + p; p = (p + bytes + 255) & ~(size_t)255; return r; };
    float* dinv    = (float*)alloc((size_t)n * 4);
    int*   off     = (int*)  alloc((size_t)n * 4);
    int*   csr_src = (int*)  alloc((size_t)E * 4);
    int*   sums    = (int*)  alloc(64 * 4);
    short* W0h     = (short*)alloc((size_t)F_in * H * 2);
    short* W0l     = (short*)alloc((size_t)F_in * H * 2);
    short* W1h     = (short*)alloc((size_t)H * H * 2);
    short* W1l     = (short*)alloc((size_t)H * H * 2);
    short* W2h     = (short*)alloc((size_t)H * H * 2);
    short* W2l     = (short*)alloc((size_t)H * H * 2);
    float* bufA    = (float*)alloc((size_t)n * 128 * 4);
    float* bufB    = (float*)alloc((size_t)n * 128 * 4);
    int*   fill    = (int*)bufB;   // alias: only used during CSR build

    const int T = 256;
    dim3 blk(T);

    // ---- CSR build + normalization + weight split
    hipMemsetAsync(off, 0, (size_t)n * 4, stream);
    hipMemsetAsync(fill, 0, (size_t)n * 4, stream);
    split_w_kernel<<<(F_in * H + T - 1) / T, blk, 0, stream>>>(W0, W0h, W0l, F_in);
    split_w_kernel<<<(H * H + T - 1) / T, blk, 0, stream>>>(W1, W1h, W1l, H);
    split_w_kernel<<<(H * H + T - 1) / T, blk, 0, stream>>>(W2, W2h, W2l, H);
    count_deg_kernel<<<(E + T - 1) / T, blk, 0, stream>>>(dst, off, E);
    int nb = (n + 1023) / 1024;
    scan1_kernel<<<nb, 1024, 0, stream>>>(off, sums, n);
    scan2_kernel<<<1, 64, 0, stream>>>(sums, nb);
    scan3_kernel<<<nb, 1024, 0, stream>>>(off, sums, n);
    make_dinv_kernel<<<(n + T - 1) / T, blk, 0, stream>>>(off, dinv, n, E);
    csr_fill_kernel<<<(E + T - 1) / T, blk, 0, stream>>>(src, dst, off, fill, csr_src, E);

    const int mblocks       = (n + 127) / 128;
    const int gather_blocks = (int)(((long long)n * 64 + T - 1) / T);

    // ---- layer 0: x(256) -> 128, relu
    gemm_mfma_kernel<<<mblocks, blk, 0, stream>>>(x, W0h, W0l, dinv, bufA, n, F_in);
    gather_kernel<<<gather_blocks, blk, 0, stream>>>(off, csr_src, dinv, bufA, b0, bufB, n, E, 1);

    // ---- layer 1: 128 -> 128, relu
    gemm_mfma_kernel<<<mblocks, blk, 0, stream>>>(bufB, W1h, W1l, dinv, bufA, n, H);
    gather_kernel<<<gather_blocks, blk, 0, stream>>>(off, csr_src, dinv, bufA, b1, bufB, n, E, 1);

    // ---- layer 2: 128 -> 128, no activation
    gemm_mfma_kernel<<<mblocks, blk, 0, stream>>>(bufB, W2h, W2l, dinv, bufA, n, H);
    gather_kernel<<<gather_blocks, blk, 0, stream>>>(off, csr_src, dinv, bufA, b2, bufB, n, E, 0);

    // ---- decode
    const int dec_blocks = (int)(((long long)EL * 64 + T - 1) / T);
    decode_kernel<<<dec_blocks, blk, 0, stream>>>(la, lb, bufB, out, EL);
}